// Round 1
// 423.221 us; speedup vs baseline: 1.0256x; 1.0256x over previous
//
#include <hip/hip_runtime.h>

// Elementwise hard clip: out = clamp(x, -0.5, 0.5), fp32.
// N = 32*2*1048576 = 67108864 elements -> 536.9 MB kernel traffic,
// roofline ~85 us at ~6.3 TB/s achievable HBM BW.
//
// Working set (512 MB) is 2x the 256 MB Infinity Cache and has zero reuse:
// use nontemporal loads/stores (global_* with nt flag) to bypass L2/L3
// write-allocate + dirty-writeback churn. 2-way unrolled grid-stride loop
// keeps two independent 16B loads in flight per thread.

// clang ext_vector_type so __builtin_nontemporal_load/store accept it
// (HIP's float4 is a struct and the builtin rejects it).
typedef float f4 __attribute__((ext_vector_type(4)));

__device__ __forceinline__ f4 clamp4(f4 v, float lo, float hi) {
    // compiles to v_med3_f32 per component
    v.x = fminf(fmaxf(v.x, lo), hi);
    v.y = fminf(fmaxf(v.y, lo), hi);
    v.z = fminf(fmaxf(v.z, lo), hi);
    v.w = fminf(fmaxf(v.w, lo), hi);
    return v;
}

__global__ __launch_bounds__(256) void clip_kernel(const float* __restrict__ x,
                                                   float* __restrict__ out,
                                                   long long n) {
    const float lo = -0.5f, hi = 0.5f;
    const long long n4 = n >> 2;  // whole float4 groups
    const long long stride = (long long)gridDim.x * blockDim.x;
    const long long tid = (long long)blockIdx.x * blockDim.x + threadIdx.x;

    const f4* __restrict__ x4 = (const f4*)x;
    f4* __restrict__ o4 = (f4*)out;

    long long i = tid;
    // 2-way unroll: issue both loads before either dependent store.
    for (; i + stride < n4; i += 2 * stride) {
        f4 a = __builtin_nontemporal_load(x4 + i);
        f4 b = __builtin_nontemporal_load(x4 + i + stride);
        a = clamp4(a, lo, hi);
        b = clamp4(b, lo, hi);
        __builtin_nontemporal_store(a, o4 + i);
        __builtin_nontemporal_store(b, o4 + i + stride);
    }
    if (i < n4) {
        f4 a = __builtin_nontemporal_load(x4 + i);
        a = clamp4(a, lo, hi);
        __builtin_nontemporal_store(a, o4 + i);
    }

    // Scalar tail (n not divisible by 4) — no-op for this problem but cheap.
    for (long long j = (n4 << 2) + tid; j < n; j += stride) {
        out[j] = fminf(fmaxf(x[j], lo), hi);
    }
}

extern "C" void kernel_launch(void* const* d_in, const int* in_sizes, int n_in,
                              void* d_out, int out_size, void* d_ws, size_t ws_size,
                              hipStream_t stream) {
    const float* x = (const float*)d_in[0];
    float* out = (float*)d_out;
    long long n = (long long)out_size;  // 67108864
    int block = 256;
    // 256 CUs x 8 workgroups (256 thr, 8 VGPR -> occupancy-max streaming grid)
    int grid = 2048;
    clip_kernel<<<grid, block, 0, stream>>>(x, out, n);
}